// Round 2
// baseline (2001.219 us; speedup 1.0000x reference)
//
#include <hip/hip_runtime.h>

#define D 32
#define BT 64          // threads per block = one wave = rows per block
#define TILE 64        // rows staged per LDS tile

__global__ void ccl_kernel(const float* __restrict__ seq,        // [B,T,D]
                           const int* __restrict__ src_len,      // [B]
                           const void* __restrict__ comb,        // [C,2] int32 (or int64)
                           float* __restrict__ out,
                           int T, int B, int C) {
    const int dir = blockIdx.x;          // 0 .. 2C-1
    const int pair = dir >> 1;
    const int flip = dir & 1;

    // Defensive dtype detection: harness converts int inputs to int32, but if
    // int64 survived, the first C long-long reads would all be in [0,B).
    const long long* c64 = (const long long*)comb;
    const int* c32 = (const int*)comb;
    bool is64 = true;
    for (int q = 0; q < C; ++q) {               // reads stay within 2C int32s
        long long v = c64[q];
        if (v < 0 || v >= (long long)B) { is64 = false; break; }
    }
    int a, b;
    if (is64) { a = (int)c64[2 * pair]; b = (int)c64[2 * pair + 1]; }
    else      { a = c32[2 * pair];      b = c32[2 * pair + 1]; }
    if (flip) { int t = a; a = b; b = t; }

    const int Lx = src_len[a] >> 2;
    const int Ly = src_len[b] >> 2;

    if (blockIdx.y * BT >= Lx) return;          // uniform early-out
    const int tid = threadIdx.x;
    const int i = blockIdx.y * BT + tid;
    const bool valid = (i < Lx);

    const float* __restrict__ xbase = seq + (size_t)a * T * D;
    const float* __restrict__ ybase = seq + (size_t)b * T * D;

    // Swizzled tile: row t's dword dw lives at lrow[t*32 + ((dw + 4t) & 31)].
    // Writes: lanes spread across bank groups; reads: wave-uniform broadcast.
    __shared__ float lrow[TILE * D];
    __shared__ float lsq[TILE];

    // x_i into registers (invalid lanes mirror a valid row; discarded later)
    float x[D];
    {
        const float* xr = xbase + (size_t)(valid ? i : (Lx - 1)) * D;
        #pragma unroll
        for (int c = 0; c < 8; ++c) {
            float4 v = *(const float4*)(xr + 4 * c);
            x[4 * c] = v.x; x[4 * c + 1] = v.y; x[4 * c + 2] = v.z; x[4 * c + 3] = v.w;
        }
    }

    auto stage = [&](const float* base, int t0, int n) {
        if (tid < n) {
            const float* r = base + (size_t)(t0 + tid) * D;
            const int rot = (4 * tid) & 31;
            float s2 = 0.f;
            #pragma unroll
            for (int c = 0; c < 8; ++c) {
                float4 v = *(const float4*)(r + 4 * c);
                *(float4*)&lrow[tid * D + ((4 * c + rot) & 31)] = v;
                s2 = fmaf(v.x, v.x, fmaf(v.y, v.y, fmaf(v.z, v.z, fmaf(v.w, v.w, s2))));
            }
            lsq[tid] = s2;
        }
    };

    // ---------------- Phase A: snn_i = softmin_j ||x_i - y_j||^2 weighted sum of y
    float m = -3.4e38f, s = 0.f;
    float acc[D];
    #pragma unroll
    for (int d = 0; d < D; ++d) acc[d] = 0.f;

    for (int j0 = 0; j0 < Ly; j0 += TILE) {
        const int nj = min(TILE, Ly - j0);
        __syncthreads();
        stage(ybase, j0, nj);
        __syncthreads();
        for (int jj = 0; jj < nj; ++jj) {
            const int rot = (4 * jj) & 31;
            float yv[D];
            #pragma unroll
            for (int c = 0; c < 8; ++c) {
                float4 v = *(const float4*)&lrow[jj * D + ((4 * c + rot) & 31)];
                yv[4 * c] = v.x; yv[4 * c + 1] = v.y; yv[4 * c + 2] = v.z; yv[4 * c + 3] = v.w;
            }
            float d0 = 0.f, d1 = 0.f, d2 = 0.f, d3 = 0.f;
            #pragma unroll
            for (int d = 0; d < D; d += 4) {
                d0 = fmaf(x[d + 0], yv[d + 0], d0);
                d1 = fmaf(x[d + 1], yv[d + 1], d1);
                d2 = fmaf(x[d + 2], yv[d + 2], d2);
                d3 = fmaf(x[d + 3], yv[d + 3], d3);
            }
            const float score = 2.f * ((d0 + d1) + (d2 + d3)) - lsq[jj];
            if (score > m) {                  // rare: rescale state
                const float scale = __expf(m - score);
                s = fmaf(s, scale, 1.f);
                #pragma unroll
                for (int d = 0; d < D; ++d) acc[d] = fmaf(acc[d], scale, yv[d]);
                m = score;
            } else {
                const float e = __expf(score - m);
                s += e;
                #pragma unroll
                for (int d = 0; d < D; ++d) acc[d] = fmaf(e, yv[d], acc[d]);
            }
        }
    }
    {
        const float inv_s = 1.f / s;
        #pragma unroll
        for (int d = 0; d < D; ++d) acc[d] *= inv_s;   // acc = snn_i
    }

    // ---------------- Phase B: softmin_k ||snn_i - x_k||^2 -> index moments (fp64)
    float mb = -3.4e38f;
    double sb = 0.0, s1 = 0.0, s2m = 0.0;
    const float fi = (float)i;
    for (int k0 = 0; k0 < Lx; k0 += TILE) {
        const int nk = min(TILE, Lx - k0);
        __syncthreads();
        stage(xbase, k0, nk);
        __syncthreads();
        for (int kk = 0; kk < nk; ++kk) {
            const int rot = (4 * kk) & 31;
            float xv[D];
            #pragma unroll
            for (int c = 0; c < 8; ++c) {
                float4 v = *(const float4*)&lrow[kk * D + ((4 * c + rot) & 31)];
                xv[4 * c] = v.x; xv[4 * c + 1] = v.y; xv[4 * c + 2] = v.z; xv[4 * c + 3] = v.w;
            }
            float d0 = 0.f, d1 = 0.f, d2 = 0.f, d3 = 0.f;
            #pragma unroll
            for (int d = 0; d < D; d += 4) {
                d0 = fmaf(acc[d + 0], xv[d + 0], d0);
                d1 = fmaf(acc[d + 1], xv[d + 1], d1);
                d2 = fmaf(acc[d + 2], xv[d + 2], d2);
                d3 = fmaf(acc[d + 3], xv[d + 3], d3);
            }
            const float score = 2.f * ((d0 + d1) + (d2 + d3)) - lsq[kk];
            const float kc = (float)(k0 + kk) - fi;   // centered index
            if (score > mb) {
                const double sc = (double)__expf(mb - score);
                const double kcd = (double)kc;
                sb = sb * sc + 1.0;
                s1 = s1 * sc + kcd;
                s2m = s2m * sc + kcd * kcd;
                mb = score;
            } else {
                const double e = (double)__expf(score - mb);
                const double kcd = (double)kc;
                sb += e;
                s1 = fma(e, kcd, s1);
                s2m = fma(e, kcd * kcd, s2m);
            }
        }
    }

    float li = 0.f;
    if (valid) {
        const double inv = 1.0 / sb;
        const double du = s1 * inv;                    // u - i
        const double var = fma(-du, du, s2m * inv);    // E[(k-i)^2] - (u-i)^2
        li = (float)(du * du / var) + 0.005f * __logf((float)var);
    }

    // wave reduce + one atomic per block (block = one wave)
    float wsum = li;
    #pragma unroll
    for (int off = 32; off > 0; off >>= 1) wsum += __shfl_down(wsum, off, 64);
    if (tid == 0) {
        atomicAdd(out, wsum * (1.0f / (float)C));
    }
}

extern "C" void kernel_launch(void* const* d_in, const int* in_sizes, int n_in,
                              void* d_out, int out_size, void* d_ws, size_t ws_size,
                              hipStream_t stream) {
    const float* seq = (const float*)d_in[0];
    const int* src_len = (const int*)d_in[1];
    const void* comb = (const void*)d_in[2];
    float* out = (float*)d_out;

    const int B = in_sizes[1];
    const int C = in_sizes[2] / 2;
    const int T = in_sizes[0] / (B * D);

    hipMemsetAsync(out, 0, sizeof(float), stream);

    dim3 grid(2 * C, (T + BT - 1) / BT);
    ccl_kernel<<<grid, BT, 0, stream>>>(seq, src_len, comb, out, T, B, C);
}

// Round 3
// 982.340 us; speedup vs baseline: 2.0372x; 2.0372x over previous
//
#include <hip/hip_runtime.h>

#define D 32

__device__ __forceinline__ void decode_pair(const void* comb, int B, int C,
                                            int pair, int flip, int& a, int& b) {
    // Harness converts ints to int32, but tolerate int64 surviving.
    const long long* c64 = (const long long*)comb;
    const int* c32 = (const int*)comb;
    bool is64 = true;
    for (int q = 0; q < C; ++q) {
        long long v = c64[q];
        if (v < 0 || v >= (long long)B) { is64 = false; break; }
    }
    if (is64) { a = (int)c64[2 * pair]; b = (int)c64[2 * pair + 1]; }
    else      { a = c32[2 * pair];      b = c32[2 * pair + 1]; }
    if (flip) { int t = a; a = b; b = t; }
}

// ---------------- K1: phase-A partial softmin over a j-chunk ----------------
// ws1 layout (field-major for coalescing): ws1[((dir*JS+js)*36 + f)*T + i]
//   f=0: m, f=1: s, f=2,3: pad, f=4..35: acc[d]
__global__ __launch_bounds__(256)
void ccl_phaseA(const float* __restrict__ seq, const int* __restrict__ src_len,
                const void* __restrict__ comb, float* __restrict__ ws1,
                int T, int B, int C, int JS) {
    const int dir = blockIdx.x, pair = dir >> 1, flip = dir & 1;
    int a, b; decode_pair(comb, B, C, pair, flip, a, b);
    const int Lx = src_len[a] >> 2, Ly = src_len[b] >> 2;
    const int r0 = blockIdx.y * 256;
    if (r0 >= Lx) return;
    const int tid = threadIdx.x;
    const int i = r0 + tid;
    const bool valid = i < Lx;
    const int js = blockIdx.z;

    const int CL = (Ly + JS - 1) / JS;
    const int j0 = js * CL, j1 = min(Ly, j0 + CL);

    const float* __restrict__ xbase = seq + (size_t)a * T * D;
    const float* __restrict__ ybase = seq + (size_t)b * T * D;

    float x2[D];   // 2*x_i
    {
        const float* xr = xbase + (size_t)(valid ? i : (Lx - 1)) * D;
        #pragma unroll
        for (int c = 0; c < 8; ++c) {
            float4 v = *(const float4*)(xr + 4 * c);
            x2[4*c] = 2.f*v.x; x2[4*c+1] = 2.f*v.y; x2[4*c+2] = 2.f*v.z; x2[4*c+3] = 2.f*v.w;
        }
    }

    __shared__ float lrow[256 * D];
    __shared__ float lsq[256];

    float m = -3.4e38f, s = 0.f;
    float acc[D];
    #pragma unroll
    for (int d = 0; d < D; ++d) acc[d] = 0.f;

    for (int t0 = j0; t0 < j1; t0 += 256) {
        const int n = min(256, j1 - t0);
        __syncthreads();
        if (tid < n) {
            const float* r = ybase + (size_t)(t0 + tid) * D;
            const int rot = (4 * tid) & 31;
            float q2 = 0.f;
            #pragma unroll
            for (int c = 0; c < 8; ++c) {
                float4 v = *(const float4*)(r + 4 * c);
                *(float4*)&lrow[tid * D + ((4 * c + rot) & 31)] = v;
                q2 = fmaf(v.x, v.x, fmaf(v.y, v.y, fmaf(v.z, v.z, fmaf(v.w, v.w, q2))));
            }
            lsq[tid] = q2;
        }
        __syncthreads();
        for (int jj = 0; jj < n; ++jj) {
            const int rot = (4 * jj) & 31;
            float yv[D];
            #pragma unroll
            for (int c = 0; c < 8; ++c) {
                float4 v = *(const float4*)&lrow[jj * D + ((4 * c + rot) & 31)];
                yv[4*c] = v.x; yv[4*c+1] = v.y; yv[4*c+2] = v.z; yv[4*c+3] = v.w;
            }
            float d0 = 0.f, d1 = 0.f, d2 = 0.f, d3 = 0.f;
            #pragma unroll
            for (int d = 0; d < D; d += 4) {
                d0 = fmaf(x2[d+0], yv[d+0], d0);
                d1 = fmaf(x2[d+1], yv[d+1], d1);
                d2 = fmaf(x2[d+2], yv[d+2], d2);
                d3 = fmaf(x2[d+3], yv[d+3], d3);
            }
            const float sc = (d0 + d1) + (d2 + d3) - lsq[jj];
            if (__any(sc > m + 8.f)) {        // rare, wave-uniform rescale
                const float mn = fmaxf(m, sc);
                const float scale = __expf(m - mn);
                const float e = __expf(sc - mn);
                s = fmaf(s, scale, e);
                #pragma unroll
                for (int d = 0; d < D; ++d) acc[d] = fmaf(acc[d], scale, e * yv[d]);
                m = mn;
            } else {                           // common path: deferred max
                const float e = __expf(sc - m);
                s += e;
                #pragma unroll
                for (int d = 0; d < D; ++d) acc[d] = fmaf(e, yv[d], acc[d]);
            }
        }
    }

    if (i < T) {
        float* slot = ws1 + ((size_t)(dir * JS + js) * 36) * T;
        slot[0 * T + i] = m;
        slot[1 * T + i] = s;
        #pragma unroll
        for (int d = 0; d < D; ++d) slot[(4 + d) * T + i] = acc[d];
    }
}

// ---------------- K1.5: merge phase-A partials -> pre-doubled snn ----------------
// ws3 layout: ws3[(dir*D + d)*T + i] = 2*snn_i[d]
__global__ __launch_bounds__(256)
void ccl_merge_snn(const float* __restrict__ ws1, const int* __restrict__ src_len,
                   const void* __restrict__ comb, float* __restrict__ ws3,
                   int T, int B, int C, int JS) {
    const int dir = blockIdx.x, pair = dir >> 1, flip = dir & 1;
    int a, b; decode_pair(comb, B, C, pair, flip, a, b);
    const int Lx = src_len[a] >> 2;
    const int r0 = blockIdx.y * 256;
    if (r0 >= Lx) return;
    const int i = r0 + threadIdx.x;
    if (i >= T) return;

    const float* base = ws1 + (size_t)dir * JS * 36 * T;
    float M = -3.4e38f;
    for (int js = 0; js < JS; ++js) M = fmaxf(M, base[((size_t)js * 36 + 0) * T + i]);
    float S = 0.f;
    float snn[D];
    #pragma unroll
    for (int d = 0; d < D; ++d) snn[d] = 0.f;
    for (int js = 0; js < JS; ++js) {
        const float* sl = base + (size_t)js * 36 * T;
        const float w = __expf(sl[0 * T + i] - M);
        S = fmaf(sl[1 * T + i], w, S);
        #pragma unroll
        for (int d = 0; d < D; ++d) snn[d] = fmaf(sl[(4 + d) * T + i], w, snn[d]);
    }
    const float k2 = 2.f / S;
    float* o = ws3 + (size_t)dir * D * T;
    #pragma unroll
    for (int d = 0; d < D; ++d) o[d * T + i] = snn[d] * k2;
}

// ---------------- K2: phase-B partial over a k-chunk (fp64 moments) ----------------
// ws2 layout (doubles): ws2[((dir*KS+ks)*4 + f)*T + i], f=0: m, 1: s, 2: s1, 3: s2
__global__ __launch_bounds__(256)
void ccl_phaseB(const float* __restrict__ seq, const int* __restrict__ src_len,
                const void* __restrict__ comb, const float* __restrict__ ws3,
                double* __restrict__ ws2, int T, int B, int C, int KS) {
    const int dir = blockIdx.x, pair = dir >> 1, flip = dir & 1;
    int a, b; decode_pair(comb, B, C, pair, flip, a, b);
    const int Lx = src_len[a] >> 2;
    const int r0 = blockIdx.y * 256;
    if (r0 >= Lx) return;
    const int tid = threadIdx.x;
    const int i = r0 + tid;
    const int ks = blockIdx.z;

    const int CL = (Lx + KS - 1) / KS;
    const int k0 = ks * CL, k1 = min(Lx, k0 + CL);

    const float* __restrict__ xbase = seq + (size_t)a * T * D;

    float sn2[D];   // 2*snn_i
    {
        const float* p = ws3 + (size_t)dir * D * T + min(i, T - 1);
        #pragma unroll
        for (int d = 0; d < D; ++d) sn2[d] = p[d * T];
    }

    __shared__ float lrow[256 * D];
    __shared__ float lsq[256];

    float m = -3.4e38f;
    double sb = 0.0, s1 = 0.0, s2 = 0.0;
    const float fi = (float)i;

    for (int t0 = k0; t0 < k1; t0 += 256) {
        const int n = min(256, k1 - t0);
        __syncthreads();
        if (tid < n) {
            const float* r = xbase + (size_t)(t0 + tid) * D;
            const int rot = (4 * tid) & 31;
            float q2 = 0.f;
            #pragma unroll
            for (int c = 0; c < 8; ++c) {
                float4 v = *(const float4*)(r + 4 * c);
                *(float4*)&lrow[tid * D + ((4 * c + rot) & 31)] = v;
                q2 = fmaf(v.x, v.x, fmaf(v.y, v.y, fmaf(v.z, v.z, fmaf(v.w, v.w, q2))));
            }
            lsq[tid] = q2;
        }
        __syncthreads();
        for (int kk = 0; kk < n; ++kk) {
            const int rot = (4 * kk) & 31;
            float xv[D];
            #pragma unroll
            for (int c = 0; c < 8; ++c) {
                float4 v = *(const float4*)&lrow[kk * D + ((4 * c + rot) & 31)];
                xv[4*c] = v.x; xv[4*c+1] = v.y; xv[4*c+2] = v.z; xv[4*c+3] = v.w;
            }
            float d0 = 0.f, d1 = 0.f, d2 = 0.f, d3 = 0.f;
            #pragma unroll
            for (int d = 0; d < D; d += 4) {
                d0 = fmaf(sn2[d+0], xv[d+0], d0);
                d1 = fmaf(sn2[d+1], xv[d+1], d1);
                d2 = fmaf(sn2[d+2], xv[d+2], d2);
                d3 = fmaf(sn2[d+3], xv[d+3], d3);
            }
            const float sc = (d0 + d1) + (d2 + d3) - lsq[kk];
            const float kc = (float)(t0 + kk) - fi;
            if (__any(sc > m + 8.f)) {
                const float mn = fmaxf(m, sc);
                const double scale = (double)__expf(m - mn);
                const double e = (double)__expf(sc - mn);
                const double kcd = (double)kc;
                sb = sb * scale + e;
                s1 = s1 * scale + e * kcd;
                s2 = s2 * scale + e * kcd * kcd;
                m = mn;
            } else {
                const double e = (double)__expf(sc - m);
                const double kcd = (double)kc;
                sb += e;
                s1 = fma(e, kcd, s1);
                s2 = fma(e * kcd, kcd, s2);
            }
        }
    }

    if (i < T) {
        double* slot = ws2 + ((size_t)(dir * KS + ks) * 4) * T;
        slot[0 * T + i] = (double)m;
        slot[1 * T + i] = sb;
        slot[2 * T + i] = s1;
        slot[3 * T + i] = s2;
    }
}

// ---------------- K3: merge phase-B partials -> li -> sum ----------------
__global__ __launch_bounds__(256)
void ccl_final(const double* __restrict__ ws2, const int* __restrict__ src_len,
               const void* __restrict__ comb, float* __restrict__ out,
               int T, int B, int C, int KS) {
    const int dir = blockIdx.x, pair = dir >> 1, flip = dir & 1;
    int a, b; decode_pair(comb, B, C, pair, flip, a, b);
    const int Lx = src_len[a] >> 2;
    const int r0 = blockIdx.y * 256;
    if (r0 >= Lx) return;
    const int tid = threadIdx.x;
    const int i = r0 + tid;
    const bool valid = i < Lx;

    float li = 0.f;
    if (valid) {
        const double* base = ws2 + (size_t)dir * KS * 4 * T;
        double M = -1e308;
        for (int ks = 0; ks < KS; ++ks) M = fmax(M, base[((size_t)ks * 4 + 0) * T + i]);
        double S = 0.0, S1 = 0.0, S2 = 0.0;
        for (int ks = 0; ks < KS; ++ks) {
            const double* sl = base + (size_t)ks * 4 * T;
            const double w = exp(sl[0 * T + i] - M);
            S  = fma(sl[1 * T + i], w, S);
            S1 = fma(sl[2 * T + i], w, S1);
            S2 = fma(sl[3 * T + i], w, S2);
        }
        const double inv = 1.0 / S;
        const double du = S1 * inv;
        const double var = fma(-du, du, S2 * inv);
        li = (float)(du * du / var) + 0.005f * __logf((float)var);
    }

    float wsum = li;
    #pragma unroll
    for (int off = 32; off > 0; off >>= 1) wsum += __shfl_down(wsum, off, 64);
    __shared__ float red[4];
    if ((tid & 63) == 0) red[tid >> 6] = wsum;
    __syncthreads();
    if (tid == 0) atomicAdd(out, (red[0] + red[1] + red[2] + red[3]) / (float)C);
}

// ---------------- Fallback: monolithic (round-2, known correct) ----------------
__global__ void ccl_mono(const float* __restrict__ seq, const int* __restrict__ src_len,
                         const void* __restrict__ comb, float* __restrict__ out,
                         int T, int B, int C) {
    const int dir = blockIdx.x, pair = dir >> 1, flip = dir & 1;
    int a, b; decode_pair(comb, B, C, pair, flip, a, b);
    const int Lx = src_len[a] >> 2, Ly = src_len[b] >> 2;
    if (blockIdx.y * 64 >= Lx) return;
    const int tid = threadIdx.x;
    const int i = blockIdx.y * 64 + tid;
    const bool valid = (i < Lx);
    const float* __restrict__ xbase = seq + (size_t)a * T * D;
    const float* __restrict__ ybase = seq + (size_t)b * T * D;
    __shared__ float lrow[64 * D];
    __shared__ float lsq[64];
    float x[D];
    {
        const float* xr = xbase + (size_t)(valid ? i : (Lx - 1)) * D;
        #pragma unroll
        for (int c = 0; c < 8; ++c) {
            float4 v = *(const float4*)(xr + 4 * c);
            x[4*c] = v.x; x[4*c+1] = v.y; x[4*c+2] = v.z; x[4*c+3] = v.w;
        }
    }
    auto stage = [&](const float* base, int t0, int n) {
        if (tid < n) {
            const float* r = base + (size_t)(t0 + tid) * D;
            const int rot = (4 * tid) & 31;
            float q2 = 0.f;
            #pragma unroll
            for (int c = 0; c < 8; ++c) {
                float4 v = *(const float4*)(r + 4 * c);
                *(float4*)&lrow[tid * D + ((4 * c + rot) & 31)] = v;
                q2 = fmaf(v.x, v.x, fmaf(v.y, v.y, fmaf(v.z, v.z, fmaf(v.w, v.w, q2))));
            }
            lsq[tid] = q2;
        }
    };
    float m = -3.4e38f, s = 0.f;
    float acc[D];
    #pragma unroll
    for (int d = 0; d < D; ++d) acc[d] = 0.f;
    for (int j0 = 0; j0 < Ly; j0 += 64) {
        const int nj = min(64, Ly - j0);
        __syncthreads(); stage(ybase, j0, nj); __syncthreads();
        for (int jj = 0; jj < nj; ++jj) {
            const int rot = (4 * jj) & 31;
            float yv[D];
            #pragma unroll
            for (int c = 0; c < 8; ++c) {
                float4 v = *(const float4*)&lrow[jj * D + ((4 * c + rot) & 31)];
                yv[4*c] = v.x; yv[4*c+1] = v.y; yv[4*c+2] = v.z; yv[4*c+3] = v.w;
            }
            float d0 = 0, d1 = 0, d2 = 0, d3 = 0;
            #pragma unroll
            for (int d = 0; d < D; d += 4) {
                d0 = fmaf(x[d], yv[d], d0); d1 = fmaf(x[d+1], yv[d+1], d1);
                d2 = fmaf(x[d+2], yv[d+2], d2); d3 = fmaf(x[d+3], yv[d+3], d3);
            }
            const float score = 2.f * ((d0 + d1) + (d2 + d3)) - lsq[jj];
            if (score > m) {
                const float scale = __expf(m - score);
                s = fmaf(s, scale, 1.f);
                #pragma unroll
                for (int d = 0; d < D; ++d) acc[d] = fmaf(acc[d], scale, yv[d]);
                m = score;
            } else {
                const float e = __expf(score - m);
                s += e;
                #pragma unroll
                for (int d = 0; d < D; ++d) acc[d] = fmaf(e, yv[d], acc[d]);
            }
        }
    }
    { const float inv_s = 1.f / s;
      #pragma unroll
      for (int d = 0; d < D; ++d) acc[d] *= inv_s; }
    float mb = -3.4e38f;
    double sb = 0.0, s1 = 0.0, s2m = 0.0;
    const float fi = (float)i;
    for (int k0 = 0; k0 < Lx; k0 += 64) {
        const int nk = min(64, Lx - k0);
        __syncthreads(); stage(xbase, k0, nk); __syncthreads();
        for (int kk = 0; kk < nk; ++kk) {
            const int rot = (4 * kk) & 31;
            float xv[D];
            #pragma unroll
            for (int c = 0; c < 8; ++c) {
                float4 v = *(const float4*)&lrow[kk * D + ((4 * c + rot) & 31)];
                xv[4*c] = v.x; xv[4*c+1] = v.y; xv[4*c+2] = v.z; xv[4*c+3] = v.w;
            }
            float d0 = 0, d1 = 0, d2 = 0, d3 = 0;
            #pragma unroll
            for (int d = 0; d < D; d += 4) {
                d0 = fmaf(acc[d], xv[d], d0); d1 = fmaf(acc[d+1], xv[d+1], d1);
                d2 = fmaf(acc[d+2], xv[d+2], d2); d3 = fmaf(acc[d+3], xv[d+3], d3);
            }
            const float score = 2.f * ((d0 + d1) + (d2 + d3)) - lsq[kk];
            const float kc = (float)(k0 + kk) - fi;
            if (score > mb) {
                const double sc = (double)__expf(mb - score);
                sb = sb * sc + 1.0; s1 = s1 * sc + (double)kc; s2m = s2m * sc + (double)kc * kc;
                mb = score;
            } else {
                const double e = (double)__expf(score - mb);
                sb += e; s1 = fma(e, (double)kc, s1); s2m = fma(e * kc, (double)kc, s2m);
            }
        }
    }
    float li = 0.f;
    if (valid) {
        const double inv = 1.0 / sb;
        const double du = s1 * inv;
        const double var = fma(-du, du, s2m * inv);
        li = (float)(du * du / var) + 0.005f * __logf((float)var);
    }
    float wsum = li;
    #pragma unroll
    for (int off = 32; off > 0; off >>= 1) wsum += __shfl_down(wsum, off, 64);
    if (tid == 0) atomicAdd(out, wsum * (1.0f / (float)C));
}

extern "C" void kernel_launch(void* const* d_in, const int* in_sizes, int n_in,
                              void* d_out, int out_size, void* d_ws, size_t ws_size,
                              hipStream_t stream) {
    const float* seq = (const float*)d_in[0];
    const int* src_len = (const int*)d_in[1];
    const void* comb = (const void*)d_in[2];
    float* out = (float*)d_out;

    const int B = in_sizes[1];
    const int C = in_sizes[2] / 2;
    const int T = in_sizes[0] / (B * D);
    const int RT = (T + 255) / 256;

    auto need = [&](int js, int ks) -> size_t {
        return ((size_t)2 * C * js * 36 * T + (size_t)2 * C * D * T) * 4
             + (size_t)2 * C * ks * 4 * T * 8;
    };
    int JS = 8, KS = 8;
    while (JS > 1 && need(JS, KS) > ws_size) { JS >>= 1; KS >>= 1; }

    hipMemsetAsync(out, 0, sizeof(float), stream);

    if (need(JS, KS) <= ws_size) {
        float* ws1 = (float*)d_ws;
        float* ws3 = ws1 + (size_t)2 * C * JS * 36 * T;
        double* ws2 = (double*)(ws3 + (size_t)2 * C * D * T);
        ccl_phaseA<<<dim3(2 * C, RT, JS), 256, 0, stream>>>(seq, src_len, comb, ws1, T, B, C, JS);
        ccl_merge_snn<<<dim3(2 * C, RT), 256, 0, stream>>>(ws1, src_len, comb, ws3, T, B, C, JS);
        ccl_phaseB<<<dim3(2 * C, RT, KS), 256, 0, stream>>>(seq, src_len, comb, ws3, ws2, T, B, C, KS);
        ccl_final<<<dim3(2 * C, RT), 256, 0, stream>>>(ws2, src_len, comb, out, T, B, C, KS);
    } else {
        dim3 grid(2 * C, (T + 63) / 64);
        ccl_mono<<<grid, 64, 0, stream>>>(seq, src_len, comb, out, T, B, C);
    }
}

// Round 4
// 848.202 us; speedup vs baseline: 2.3594x; 1.1581x over previous
//
#include <hip/hip_runtime.h>

#define D 32

__device__ __forceinline__ void decode_pair(const void* comb, int B, int C,
                                            int pair, int flip, int& a, int& b) {
    const long long* c64 = (const long long*)comb;
    const int* c32 = (const int*)comb;
    bool is64 = true;
    for (int q = 0; q < C; ++q) {
        long long v = c64[q];
        if (v < 0 || v >= (long long)B) { is64 = false; break; }
    }
    if (is64) { a = (int)c64[2 * pair]; b = (int)c64[2 * pair + 1]; }
    else      { a = c32[2 * pair];      b = c32[2 * pair + 1]; }
    if (flip) { int t = a; a = b; b = t; }
}

// ---------------- K0: per-row squared norms ----------------
__global__ __launch_bounds__(64)
void row_norms(const float* __restrict__ seq, float* __restrict__ norms, int nrows) {
    const int r = blockIdx.x * 64 + threadIdx.x;
    if (r >= nrows) return;
    const float* p = seq + (size_t)r * D;
    float s = 0.f;
    #pragma unroll
    for (int c = 0; c < 8; ++c) {
        float4 v = *(const float4*)(p + 4 * c);
        s = fmaf(v.x, v.x, fmaf(v.y, v.y, fmaf(v.z, v.z, fmaf(v.w, v.w, s))));
    }
    norms[r] = s;
}

// ---------------- K1: phase-A partial softmin over a j-chunk ----------------
// One lane = one row i; the y-row is wave-uniform -> scalar loads (SGPRs).
// ws1 layout: ws1[((dir*JS+js)*36 + f)*T + i]  f=0:m f=1:s f=4..35:acc
__global__ __launch_bounds__(256)
void ccl_phaseA(const float* __restrict__ seq, const int* __restrict__ src_len,
                const void* __restrict__ comb, const float* __restrict__ norms,
                float* __restrict__ ws1, int T, int B, int C, int JS) {
    const int dir = blockIdx.x, pair = dir >> 1, flip = dir & 1;
    int a, b; decode_pair(comb, B, C, pair, flip, a, b);
    const int Lx = src_len[a] >> 2, Ly = src_len[b] >> 2;
    const int r0 = blockIdx.y * 256;
    if (r0 >= Lx) return;
    const int tid = threadIdx.x;
    const int i = r0 + tid;
    const bool valid = i < Lx;
    const int js = blockIdx.z;
    const int CL = (Ly + JS - 1) / JS;
    const int j0 = js * CL, j1 = min(Ly, j0 + CL);

    const float* __restrict__ xbase = seq + (size_t)a * T * D;
    const float* __restrict__ ybase = seq + (size_t)b * T * D;
    const float* __restrict__ ny = norms + (size_t)b * T;

    float x2[D];   // 2*x_i (per lane)
    {
        const float* xr = xbase + (size_t)(valid ? i : (Lx - 1)) * D;
        #pragma unroll
        for (int c = 0; c < 8; ++c) {
            float4 v = *(const float4*)(xr + 4 * c);
            x2[4*c] = 2.f*v.x; x2[4*c+1] = 2.f*v.y; x2[4*c+2] = 2.f*v.z; x2[4*c+3] = 2.f*v.w;
        }
    }

    float m = -3.4e38f, s = 0.f;
    float acc[D];
    #pragma unroll
    for (int d = 0; d < D; ++d) acc[d] = 0.f;

    for (int j = j0; j < j1; ++j) {
        const float* yr = ybase + (size_t)j * D;   // uniform address -> s_load
        float yv[D];
        #pragma unroll
        for (int d = 0; d < D; ++d) yv[d] = yr[d];
        float d0 = -ny[j], d1 = 0.f, d2 = 0.f, d3 = 0.f;
        #pragma unroll
        for (int d = 0; d < D; d += 4) {
            d0 = fmaf(x2[d+0], yv[d+0], d0);
            d1 = fmaf(x2[d+1], yv[d+1], d1);
            d2 = fmaf(x2[d+2], yv[d+2], d2);
            d3 = fmaf(x2[d+3], yv[d+3], d3);
        }
        const float sc = (d0 + d1) + (d2 + d3);
        if (__any(sc > m + 8.f)) {        // rare, wave-uniform rescale
            const float mn = fmaxf(m, sc);
            const float scale = __expf(m - mn);
            const float e = __expf(sc - mn);
            s = fmaf(s, scale, e);
            #pragma unroll
            for (int d = 0; d < D; ++d) acc[d] = fmaf(acc[d], scale, e * yv[d]);
            m = mn;
        } else {                           // deferred-max common path
            const float e = __expf(sc - m);
            s += e;
            #pragma unroll
            for (int d = 0; d < D; ++d) acc[d] = fmaf(e, yv[d], acc[d]);
        }
    }

    if (i < T) {
        float* slot = ws1 + ((size_t)(dir * JS + js) * 36) * T;
        slot[0 * T + i] = m;
        slot[1 * T + i] = s;
        #pragma unroll
        for (int d = 0; d < D; ++d) slot[(4 + d) * T + i] = acc[d];
    }
}

// ---------------- K1.5: merge phase-A partials -> pre-doubled snn ----------------
// ws3[(dir*D + d)*T + i] = 2*snn_i[d]
__global__ __launch_bounds__(256)
void ccl_merge_snn(const float* __restrict__ ws1, const int* __restrict__ src_len,
                   const void* __restrict__ comb, float* __restrict__ ws3,
                   int T, int B, int C, int JS) {
    const int dir = blockIdx.x, pair = dir >> 1, flip = dir & 1;
    int a, b; decode_pair(comb, B, C, pair, flip, a, b);
    const int Lx = src_len[a] >> 2;
    const int r0 = blockIdx.y * 256;
    if (r0 >= Lx) return;
    const int i = r0 + threadIdx.x;
    if (i >= T) return;

    const float* base = ws1 + (size_t)dir * JS * 36 * T;
    float M = -3.4e38f;
    for (int js = 0; js < JS; ++js) M = fmaxf(M, base[((size_t)js * 36 + 0) * T + i]);
    float S = 0.f;
    float snn[D];
    #pragma unroll
    for (int d = 0; d < D; ++d) snn[d] = 0.f;
    for (int js = 0; js < JS; ++js) {
        const float* sl = base + (size_t)js * 36 * T;
        const float w = __expf(sl[0 * T + i] - M);
        S = fmaf(sl[1 * T + i], w, S);
        #pragma unroll
        for (int d = 0; d < D; ++d) snn[d] = fmaf(sl[(4 + d) * T + i], w, snn[d]);
    }
    const float k2 = 2.f / S;
    float* o = ws3 + (size_t)dir * D * T;
    #pragma unroll
    for (int d = 0; d < D; ++d) o[d * T + i] = snn[d] * k2;
}

// ---------------- K2: phase-B partial over a k-chunk (fp64 moments) ----------------
// ws2 (doubles): ws2[((dir*KS+ks)*4 + f)*T + i], f=0:m 1:s 2:s1 3:s2
__global__ __launch_bounds__(256)
void ccl_phaseB(const float* __restrict__ seq, const int* __restrict__ src_len,
                const void* __restrict__ comb, const float* __restrict__ norms,
                const float* __restrict__ ws3, double* __restrict__ ws2,
                int T, int B, int C, int KS) {
    const int dir = blockIdx.x, pair = dir >> 1, flip = dir & 1;
    int a, b; decode_pair(comb, B, C, pair, flip, a, b);
    const int Lx = src_len[a] >> 2;
    const int r0 = blockIdx.y * 256;
    if (r0 >= Lx) return;
    const int tid = threadIdx.x;
    const int i = r0 + tid;
    const int ks = blockIdx.z;
    const int CL = (Lx + KS - 1) / KS;
    const int k0 = ks * CL, k1 = min(Lx, k0 + CL);

    const float* __restrict__ xbase = seq + (size_t)a * T * D;
    const float* __restrict__ nx = norms + (size_t)a * T;

    float sn2[D];   // 2*snn_i (per lane)
    {
        const float* p = ws3 + (size_t)dir * D * T + min(i, T - 1);
        #pragma unroll
        for (int d = 0; d < D; ++d) sn2[d] = p[d * T];
    }

    float m = -3.4e38f;
    double sb = 0.0, s1 = 0.0, s2 = 0.0;
    const float fi = (float)i;

    for (int k = k0; k < k1; ++k) {
        const float* xr = xbase + (size_t)k * D;   // uniform -> s_load
        float xv[D];
        #pragma unroll
        for (int d = 0; d < D; ++d) xv[d] = xr[d];
        float d0 = -nx[k], d1 = 0.f, d2 = 0.f, d3 = 0.f;
        #pragma unroll
        for (int d = 0; d < D; d += 4) {
            d0 = fmaf(sn2[d+0], xv[d+0], d0);
            d1 = fmaf(sn2[d+1], xv[d+1], d1);
            d2 = fmaf(sn2[d+2], xv[d+2], d2);
            d3 = fmaf(sn2[d+3], xv[d+3], d3);
        }
        const float sc = (d0 + d1) + (d2 + d3);
        const float kc = (float)k - fi;
        if (__any(sc > m + 8.f)) {
            const float mn = fmaxf(m, sc);
            const double scale = (double)__expf(m - mn);
            const double e = (double)__expf(sc - mn);
            const double kcd = (double)kc;
            sb = sb * scale + e;
            s1 = s1 * scale + e * kcd;
            s2 = s2 * scale + e * kcd * kcd;
            m = mn;
        } else {
            const double e = (double)__expf(sc - m);
            const double kcd = (double)kc;
            sb += e;
            s1 = fma(e, kcd, s1);
            s2 = fma(e * kcd, kcd, s2);
        }
    }

    if (i < T) {
        double* slot = ws2 + ((size_t)(dir * KS + ks) * 4) * T;
        slot[0 * T + i] = (double)m;
        slot[1 * T + i] = sb;
        slot[2 * T + i] = s1;
        slot[3 * T + i] = s2;
    }
}

// ---------------- K3: merge phase-B partials -> li -> sum ----------------
__global__ __launch_bounds__(256)
void ccl_final(const double* __restrict__ ws2, const int* __restrict__ src_len,
               const void* __restrict__ comb, float* __restrict__ out,
               int T, int B, int C, int KS) {
    const int dir = blockIdx.x, pair = dir >> 1, flip = dir & 1;
    int a, b; decode_pair(comb, B, C, pair, flip, a, b);
    const int Lx = src_len[a] >> 2;
    const int r0 = blockIdx.y * 256;
    if (r0 >= Lx) return;
    const int tid = threadIdx.x;
    const int i = r0 + tid;
    const bool valid = i < Lx;

    float li = 0.f;
    if (valid) {
        const double* base = ws2 + (size_t)dir * KS * 4 * T;
        double M = -1e308;
        for (int ks = 0; ks < KS; ++ks) M = fmax(M, base[((size_t)ks * 4 + 0) * T + i]);
        double S = 0.0, S1 = 0.0, S2 = 0.0;
        for (int ks = 0; ks < KS; ++ks) {
            const double* sl = base + (size_t)ks * 4 * T;
            const double w = exp(sl[0 * T + i] - M);
            S  = fma(sl[1 * T + i], w, S);
            S1 = fma(sl[2 * T + i], w, S1);
            S2 = fma(sl[3 * T + i], w, S2);
        }
        const double inv = 1.0 / S;
        const double du = S1 * inv;
        const double var = fma(-du, du, S2 * inv);
        li = (float)(du * du / var) + 0.005f * __logf((float)var);
    }

    float wsum = li;
    #pragma unroll
    for (int off = 32; off > 0; off >>= 1) wsum += __shfl_down(wsum, off, 64);
    __shared__ float red[4];
    if ((tid & 63) == 0) red[tid >> 6] = wsum;
    __syncthreads();
    if (tid == 0) atomicAdd(out, (red[0] + red[1] + red[2] + red[3]) / (float)C);
}

// ---------------- Fallback: monolithic (round-2, known correct) ----------------
__global__ void ccl_mono(const float* __restrict__ seq, const int* __restrict__ src_len,
                         const void* __restrict__ comb, float* __restrict__ out,
                         int T, int B, int C) {
    const int dir = blockIdx.x, pair = dir >> 1, flip = dir & 1;
    int a, b; decode_pair(comb, B, C, pair, flip, a, b);
    const int Lx = src_len[a] >> 2, Ly = src_len[b] >> 2;
    if (blockIdx.y * 64 >= Lx) return;
    const int tid = threadIdx.x;
    const int i = blockIdx.y * 64 + tid;
    const bool valid = (i < Lx);
    const float* __restrict__ xbase = seq + (size_t)a * T * D;
    const float* __restrict__ ybase = seq + (size_t)b * T * D;
    float x[D];
    {
        const float* xr = xbase + (size_t)(valid ? i : (Lx - 1)) * D;
        #pragma unroll
        for (int c = 0; c < 8; ++c) {
            float4 v = *(const float4*)(xr + 4 * c);
            x[4*c] = 2.f*v.x; x[4*c+1] = 2.f*v.y; x[4*c+2] = 2.f*v.z; x[4*c+3] = 2.f*v.w;
        }
    }
    float m = -3.4e38f, s = 0.f;
    float acc[D];
    #pragma unroll
    for (int d = 0; d < D; ++d) acc[d] = 0.f;
    for (int j = 0; j < Ly; ++j) {
        const float* yr = ybase + (size_t)j * D;
        float yv[D]; float q2 = 0.f;
        #pragma unroll
        for (int d = 0; d < D; ++d) { yv[d] = yr[d]; q2 = fmaf(yv[d], yv[d], q2); }
        float d0 = -q2, d1 = 0.f, d2 = 0.f, d3 = 0.f;
        #pragma unroll
        for (int d = 0; d < D; d += 4) {
            d0 = fmaf(x[d], yv[d], d0); d1 = fmaf(x[d+1], yv[d+1], d1);
            d2 = fmaf(x[d+2], yv[d+2], d2); d3 = fmaf(x[d+3], yv[d+3], d3);
        }
        const float sc = (d0 + d1) + (d2 + d3);
        if (__any(sc > m + 8.f)) {
            const float mn = fmaxf(m, sc);
            const float scale = __expf(m - mn);
            const float e = __expf(sc - mn);
            s = fmaf(s, scale, e);
            #pragma unroll
            for (int d = 0; d < D; ++d) acc[d] = fmaf(acc[d], scale, e * yv[d]);
            m = mn;
        } else {
            const float e = __expf(sc - m);
            s += e;
            #pragma unroll
            for (int d = 0; d < D; ++d) acc[d] = fmaf(e, yv[d], acc[d]);
        }
    }
    { const float inv_s = 2.f / s;
      #pragma unroll
      for (int d = 0; d < D; ++d) acc[d] *= inv_s; }
    float mb = -3.4e38f;
    double sb = 0.0, s1 = 0.0, s2m = 0.0;
    const float fi = (float)i;
    for (int k = 0; k < Lx; ++k) {
        const float* xr = xbase + (size_t)k * D;
        float xv[D]; float q2 = 0.f;
        #pragma unroll
        for (int d = 0; d < D; ++d) { xv[d] = xr[d]; q2 = fmaf(xv[d], xv[d], q2); }
        float d0 = -q2, d1 = 0.f, d2 = 0.f, d3 = 0.f;
        #pragma unroll
        for (int d = 0; d < D; d += 4) {
            d0 = fmaf(acc[d], xv[d], d0); d1 = fmaf(acc[d+1], xv[d+1], d1);
            d2 = fmaf(acc[d+2], xv[d+2], d2); d3 = fmaf(acc[d+3], xv[d+3], d3);
        }
        const float sc = (d0 + d1) + (d2 + d3);
        const float kc = (float)k - fi;
        if (__any(sc > mb + 8.f)) {
            const float mn = fmaxf(mb, sc);
            const double scale = (double)__expf(mb - mn);
            const double e = (double)__expf(sc - mn);
            sb = sb * scale + e; s1 = s1 * scale + e * kc; s2m = s2m * scale + e * kc * kc;
            mb = mn;
        } else {
            const double e = (double)__expf(sc - mb);
            sb += e; s1 = fma(e, (double)kc, s1); s2m = fma(e * kc, (double)kc, s2m);
        }
    }
    float li = 0.f;
    if (valid) {
        const double inv = 1.0 / sb;
        const double du = s1 * inv;
        const double var = fma(-du, du, s2m * inv);
        li = (float)(du * du / var) + 0.005f * __logf((float)var);
    }
    float wsum = li;
    #pragma unroll
    for (int off = 32; off > 0; off >>= 1) wsum += __shfl_down(wsum, off, 64);
    if (tid == 0) atomicAdd(out, wsum * (1.0f / (float)C));
}

extern "C" void kernel_launch(void* const* d_in, const int* in_sizes, int n_in,
                              void* d_out, int out_size, void* d_ws, size_t ws_size,
                              hipStream_t stream) {
    const float* seq = (const float*)d_in[0];
    const int* src_len = (const int*)d_in[1];
    const void* comb = (const void*)d_in[2];
    float* out = (float*)d_out;

    const int B = in_sizes[1];
    const int C = in_sizes[2] / 2;
    const int T = in_sizes[0] / (B * D);
    const int RT = (T + 255) / 256;
    const int nrows = B * T;

    auto need = [&](int js, int ks) -> size_t {
        return (size_t)nrows * 4
             + ((size_t)2 * C * js * 36 * T + (size_t)2 * C * D * T) * 4
             + (size_t)2 * C * ks * 4 * T * 8;
    };
    int JS = 8, KS = 8;
    while (JS > 1 && need(JS, KS) > ws_size) { JS >>= 1; KS >>= 1; }

    hipMemsetAsync(out, 0, sizeof(float), stream);

    if (need(JS, KS) <= ws_size) {
        float* norms = (float*)d_ws;
        float* ws1 = norms + nrows;
        float* ws3 = ws1 + (size_t)2 * C * JS * 36 * T;
        double* ws2 = (double*)(ws3 + (size_t)2 * C * D * T);
        row_norms<<<(nrows + 63) / 64, 64, 0, stream>>>(seq, norms, nrows);
        ccl_phaseA<<<dim3(2 * C, RT, JS), 256, 0, stream>>>(seq, src_len, comb, norms, ws1, T, B, C, JS);
        ccl_merge_snn<<<dim3(2 * C, RT), 256, 0, stream>>>(ws1, src_len, comb, ws3, T, B, C, JS);
        ccl_phaseB<<<dim3(2 * C, RT, KS), 256, 0, stream>>>(seq, src_len, comb, norms, ws3, ws2, T, B, C, KS);
        ccl_final<<<dim3(2 * C, RT), 256, 0, stream>>>(ws2, src_len, comb, out, T, B, C, KS);
    } else {
        dim3 grid(2 * C, (T + 63) / 64);
        ccl_mono<<<grid, 64, 0, stream>>>(seq, src_len, comb, out, T, B, C);
    }
}

// Round 5
// 838.278 us; speedup vs baseline: 2.3873x; 1.0118x over previous
//
#include <hip/hip_runtime.h>

#define D 32
#define NT 128   // threads per phase-kernel block (2 waves) -> full residency

__device__ __forceinline__ void decode_pair(const void* comb, int B, int C,
                                            int pair, int flip, int& a, int& b) {
    const long long* c64 = (const long long*)comb;
    const int* c32 = (const int*)comb;
    bool is64 = true;
    for (int q = 0; q < C; ++q) {
        long long v = c64[q];
        if (v < 0 || v >= (long long)B) { is64 = false; break; }
    }
    if (is64) { a = (int)c64[2 * pair]; b = (int)c64[2 * pair + 1]; }
    else      { a = c32[2 * pair];      b = c32[2 * pair + 1]; }
    if (flip) { int t = a; a = b; b = t; }
}

// ---------------- K0: per-row squared norms ----------------
__global__ __launch_bounds__(64)
void row_norms(const float* __restrict__ seq, float* __restrict__ norms, int nrows) {
    const int r = blockIdx.x * 64 + threadIdx.x;
    if (r >= nrows) return;
    const float* p = seq + (size_t)r * D;
    float s = 0.f;
    #pragma unroll
    for (int c = 0; c < 8; ++c) {
        float4 v = *(const float4*)(p + 4 * c);
        s = fmaf(v.x, v.x, fmaf(v.y, v.y, fmaf(v.z, v.z, fmaf(v.w, v.w, s))));
    }
    norms[r] = s;
}

// ---------------- K1: phase-A partial softmin over a j-chunk ----------------
// ws1 layout: ws1[((dir*JS+js)*36 + f)*T + i]  f=0:m f=1:s f=4..35:acc
__global__ __launch_bounds__(NT)
void ccl_phaseA(const float* __restrict__ seq, const int* __restrict__ src_len,
                const void* __restrict__ comb, const float* __restrict__ norms,
                float* __restrict__ ws1, int T, int B, int C, int JS) {
    const int dir = blockIdx.x, pair = dir >> 1, flip = dir & 1;
    int a, b; decode_pair(comb, B, C, pair, flip, a, b);
    const int Lx = src_len[a] >> 2, Ly = src_len[b] >> 2;
    const int r0 = blockIdx.y * NT;
    if (r0 >= Lx) return;
    const int tid = threadIdx.x;
    const int i = r0 + tid;
    const bool valid = i < Lx;
    const int js = blockIdx.z;
    const int CL = (Ly + JS - 1) / JS;
    const int j0 = js * CL, j1 = min(Ly, j0 + CL);

    const float* __restrict__ xbase = seq + (size_t)a * T * D;
    const float* __restrict__ ybase = seq + (size_t)b * T * D;
    const float* __restrict__ ny = norms + (size_t)b * T;

    float x2[D];   // 2*x_i (per lane)
    {
        const float* xr = xbase + (size_t)(valid ? i : (Lx - 1)) * D;
        #pragma unroll
        for (int c = 0; c < 8; ++c) {
            float4 v = *(const float4*)(xr + 4 * c);
            x2[4*c] = 2.f*v.x; x2[4*c+1] = 2.f*v.y; x2[4*c+2] = 2.f*v.z; x2[4*c+3] = 2.f*v.w;
        }
    }

    float m = -3.4e38f, s = 0.f;
    float acc[D];
    #pragma unroll
    for (int d = 0; d < D; ++d) acc[d] = 0.f;

    for (int j = j0; j < j1; ++j) {
        const float* yr = ybase + (size_t)j * D;   // wave-uniform address
        float yv[D];
        #pragma unroll
        for (int d = 0; d < D; ++d) yv[d] = yr[d];
        float d0 = -ny[j], d1 = 0.f, d2 = 0.f, d3 = 0.f;
        #pragma unroll
        for (int d = 0; d < D; d += 4) {
            d0 = fmaf(x2[d+0], yv[d+0], d0);
            d1 = fmaf(x2[d+1], yv[d+1], d1);
            d2 = fmaf(x2[d+2], yv[d+2], d2);
            d3 = fmaf(x2[d+3], yv[d+3], d3);
        }
        const float sc = (d0 + d1) + (d2 + d3);
        if (__any(sc > m + 8.f)) {        // rare, wave-uniform rescale
            const float mn = fmaxf(m, sc);
            const float scale = __expf(m - mn);
            const float e = __expf(sc - mn);
            s = fmaf(s, scale, e);
            #pragma unroll
            for (int d = 0; d < D; ++d) acc[d] = fmaf(acc[d], scale, e * yv[d]);
            m = mn;
        } else {                           // deferred-max common path
            const float e = __expf(sc - m);
            s += e;
            #pragma unroll
            for (int d = 0; d < D; ++d) acc[d] = fmaf(e, yv[d], acc[d]);
        }
    }

    if (i < T) {
        float* slot = ws1 + ((size_t)(dir * JS + js) * 36) * T;
        slot[0 * T + i] = m;
        slot[1 * T + i] = s;
        #pragma unroll
        for (int d = 0; d < D; ++d) slot[(4 + d) * T + i] = acc[d];
    }
}

// ---------------- K1.5: merge phase-A partials -> pre-doubled snn ----------------
// ws3[(dir*D + d)*T + i] = 2*snn_i[d]
__global__ __launch_bounds__(256)
void ccl_merge_snn(const float* __restrict__ ws1, const int* __restrict__ src_len,
                   const void* __restrict__ comb, float* __restrict__ ws3,
                   int T, int B, int C, int JS) {
    const int dir = blockIdx.x, pair = dir >> 1, flip = dir & 1;
    int a, b; decode_pair(comb, B, C, pair, flip, a, b);
    const int Lx = src_len[a] >> 2;
    const int r0 = blockIdx.y * 256;
    if (r0 >= Lx) return;
    const int i = r0 + threadIdx.x;
    if (i >= T) return;

    const float* base = ws1 + (size_t)dir * JS * 36 * T;
    float M = -3.4e38f;
    for (int js = 0; js < JS; ++js) M = fmaxf(M, base[((size_t)js * 36 + 0) * T + i]);
    float S = 0.f;
    float snn[D];
    #pragma unroll
    for (int d = 0; d < D; ++d) snn[d] = 0.f;
    for (int js = 0; js < JS; ++js) {
        const float* sl = base + (size_t)js * 36 * T;
        const float w = __expf(sl[0 * T + i] - M);
        S = fmaf(sl[1 * T + i], w, S);
        #pragma unroll
        for (int d = 0; d < D; ++d) snn[d] = fmaf(sl[(4 + d) * T + i], w, snn[d]);
    }
    const float k2 = 2.f / S;
    float* o = ws3 + (size_t)dir * D * T;
    #pragma unroll
    for (int d = 0; d < D; ++d) o[d * T + i] = snn[d] * k2;
}

// ---------------- K2: phase-B partial over a k-chunk (fp64 moments) ----------------
// ws2 (doubles): ws2[((dir*KS+ks)*4 + f)*T + i], f=0:m 1:s 2:s1 3:s2
__global__ __launch_bounds__(NT)
void ccl_phaseB(const float* __restrict__ seq, const int* __restrict__ src_len,
                const void* __restrict__ comb, const float* __restrict__ norms,
                const float* __restrict__ ws3, double* __restrict__ ws2,
                int T, int B, int C, int KS) {
    const int dir = blockIdx.x, pair = dir >> 1, flip = dir & 1;
    int a, b; decode_pair(comb, B, C, pair, flip, a, b);
    const int Lx = src_len[a] >> 2;
    const int r0 = blockIdx.y * NT;
    if (r0 >= Lx) return;
    const int tid = threadIdx.x;
    const int i = r0 + tid;
    const int ks = blockIdx.z;
    const int CL = (Lx + KS - 1) / KS;
    const int k0 = ks * CL, k1 = min(Lx, k0 + CL);

    const float* __restrict__ xbase = seq + (size_t)a * T * D;
    const float* __restrict__ nx = norms + (size_t)a * T;

    float sn2[D];   // 2*snn_i (per lane)
    {
        const float* p = ws3 + (size_t)dir * D * T + min(i, T - 1);
        #pragma unroll
        for (int d = 0; d < D; ++d) sn2[d] = p[d * T];
    }

    float m = -3.4e38f;
    double sb = 0.0, s1 = 0.0, s2 = 0.0;
    const float fi = (float)i;

    for (int k = k0; k < k1; ++k) {
        const float* xr = xbase + (size_t)k * D;   // wave-uniform address
        float xv[D];
        #pragma unroll
        for (int d = 0; d < D; ++d) xv[d] = xr[d];
        float d0 = -nx[k], d1 = 0.f, d2 = 0.f, d3 = 0.f;
        #pragma unroll
        for (int d = 0; d < D; d += 4) {
            d0 = fmaf(sn2[d+0], xv[d+0], d0);
            d1 = fmaf(sn2[d+1], xv[d+1], d1);
            d2 = fmaf(sn2[d+2], xv[d+2], d2);
            d3 = fmaf(sn2[d+3], xv[d+3], d3);
        }
        const float sc = (d0 + d1) + (d2 + d3);
        const float kc = (float)k - fi;
        if (__any(sc > m + 8.f)) {
            const float mn = fmaxf(m, sc);
            const double scale = (double)__expf(m - mn);
            const double e = (double)__expf(sc - mn);
            const double kcd = (double)kc;
            sb = sb * scale + e;
            s1 = s1 * scale + e * kcd;
            s2 = s2 * scale + e * kcd * kcd;
            m = mn;
        } else {
            const double e = (double)__expf(sc - m);
            const double kcd = (double)kc;
            sb += e;
            s1 = fma(e, kcd, s1);
            s2 = fma(e * kcd, kcd, s2);
        }
    }

    if (i < T) {
        double* slot = ws2 + ((size_t)(dir * KS + ks) * 4) * T;
        slot[0 * T + i] = (double)m;
        slot[1 * T + i] = sb;
        slot[2 * T + i] = s1;
        slot[3 * T + i] = s2;
    }
}

// ---------------- K3: merge phase-B partials -> li -> sum ----------------
__global__ __launch_bounds__(256)
void ccl_final(const double* __restrict__ ws2, const int* __restrict__ src_len,
               const void* __restrict__ comb, float* __restrict__ out,
               int T, int B, int C, int KS) {
    const int dir = blockIdx.x, pair = dir >> 1, flip = dir & 1;
    int a, b; decode_pair(comb, B, C, pair, flip, a, b);
    const int Lx = src_len[a] >> 2;
    const int r0 = blockIdx.y * 256;
    if (r0 >= Lx) return;
    const int tid = threadIdx.x;
    const int i = r0 + tid;
    const bool valid = i < Lx;

    float li = 0.f;
    if (valid) {
        const double* base = ws2 + (size_t)dir * KS * 4 * T;
        double M = -1e308;
        for (int ks = 0; ks < KS; ++ks) M = fmax(M, base[((size_t)ks * 4 + 0) * T + i]);
        double S = 0.0, S1 = 0.0, S2 = 0.0;
        for (int ks = 0; ks < KS; ++ks) {
            const double* sl = base + (size_t)ks * 4 * T;
            const double w = exp(sl[0 * T + i] - M);
            S  = fma(sl[1 * T + i], w, S);
            S1 = fma(sl[2 * T + i], w, S1);
            S2 = fma(sl[3 * T + i], w, S2);
        }
        const double inv = 1.0 / S;
        const double du = S1 * inv;
        const double var = fma(-du, du, S2 * inv);
        li = (float)(du * du / var) + 0.005f * __logf((float)var);
    }

    float wsum = li;
    #pragma unroll
    for (int off = 32; off > 0; off >>= 1) wsum += __shfl_down(wsum, off, 64);
    __shared__ float red[4];
    if ((tid & 63) == 0) red[tid >> 6] = wsum;
    __syncthreads();
    if (tid == 0) atomicAdd(out, (red[0] + red[1] + red[2] + red[3]) / (float)C);
}

// ---------------- Fallback: monolithic (known correct) ----------------
__global__ void ccl_mono(const float* __restrict__ seq, const int* __restrict__ src_len,
                         const void* __restrict__ comb, float* __restrict__ out,
                         int T, int B, int C) {
    const int dir = blockIdx.x, pair = dir >> 1, flip = dir & 1;
    int a, b; decode_pair(comb, B, C, pair, flip, a, b);
    const int Lx = src_len[a] >> 2, Ly = src_len[b] >> 2;
    if (blockIdx.y * 64 >= Lx) return;
    const int tid = threadIdx.x;
    const int i = blockIdx.y * 64 + tid;
    const bool valid = (i < Lx);
    const float* __restrict__ xbase = seq + (size_t)a * T * D;
    const float* __restrict__ ybase = seq + (size_t)b * T * D;
    float x[D];
    {
        const float* xr = xbase + (size_t)(valid ? i : (Lx - 1)) * D;
        #pragma unroll
        for (int c = 0; c < 8; ++c) {
            float4 v = *(const float4*)(xr + 4 * c);
            x[4*c] = 2.f*v.x; x[4*c+1] = 2.f*v.y; x[4*c+2] = 2.f*v.z; x[4*c+3] = 2.f*v.w;
        }
    }
    float m = -3.4e38f, s = 0.f;
    float acc[D];
    #pragma unroll
    for (int d = 0; d < D; ++d) acc[d] = 0.f;
    for (int j = 0; j < Ly; ++j) {
        const float* yr = ybase + (size_t)j * D;
        float yv[D]; float q2 = 0.f;
        #pragma unroll
        for (int d = 0; d < D; ++d) { yv[d] = yr[d]; q2 = fmaf(yv[d], yv[d], q2); }
        float d0 = -q2, d1 = 0.f, d2 = 0.f, d3 = 0.f;
        #pragma unroll
        for (int d = 0; d < D; d += 4) {
            d0 = fmaf(x[d], yv[d], d0); d1 = fmaf(x[d+1], yv[d+1], d1);
            d2 = fmaf(x[d+2], yv[d+2], d2); d3 = fmaf(x[d+3], yv[d+3], d3);
        }
        const float sc = (d0 + d1) + (d2 + d3);
        if (__any(sc > m + 8.f)) {
            const float mn = fmaxf(m, sc);
            const float scale = __expf(m - mn);
            const float e = __expf(sc - mn);
            s = fmaf(s, scale, e);
            #pragma unroll
            for (int d = 0; d < D; ++d) acc[d] = fmaf(acc[d], scale, e * yv[d]);
            m = mn;
        } else {
            const float e = __expf(sc - m);
            s += e;
            #pragma unroll
            for (int d = 0; d < D; ++d) acc[d] = fmaf(e, yv[d], acc[d]);
        }
    }
    { const float inv_s = 2.f / s;
      #pragma unroll
      for (int d = 0; d < D; ++d) acc[d] *= inv_s; }
    float mb = -3.4e38f;
    double sb = 0.0, s1 = 0.0, s2m = 0.0;
    const float fi = (float)i;
    for (int k = 0; k < Lx; ++k) {
        const float* xr = xbase + (size_t)k * D;
        float xv[D]; float q2 = 0.f;
        #pragma unroll
        for (int d = 0; d < D; ++d) { xv[d] = xr[d]; q2 = fmaf(xv[d], xv[d], q2); }
        float d0 = -q2, d1 = 0.f, d2 = 0.f, d3 = 0.f;
        #pragma unroll
        for (int d = 0; d < D; d += 4) {
            d0 = fmaf(acc[d], xv[d], d0); d1 = fmaf(acc[d+1], xv[d+1], d1);
            d2 = fmaf(acc[d+2], xv[d+2], d2); d3 = fmaf(acc[d+3], xv[d+3], d3);
        }
        const float sc = (d0 + d1) + (d2 + d3);
        const float kc = (float)k - fi;
        if (__any(sc > mb + 8.f)) {
            const float mn = fmaxf(mb, sc);
            const double scale = (double)__expf(mb - mn);
            const double e = (double)__expf(sc - mn);
            sb = sb * scale + e; s1 = s1 * scale + e * kc; s2m = s2m * scale + e * kc * kc;
            mb = mn;
        } else {
            const double e = (double)__expf(sc - mb);
            sb += e; s1 = fma(e, (double)kc, s1); s2m = fma(e * kc, (double)kc, s2m);
        }
    }
    float li = 0.f;
    if (valid) {
        const double inv = 1.0 / sb;
        const double du = s1 * inv;
        const double var = fma(-du, du, s2m * inv);
        li = (float)(du * du / var) + 0.005f * __logf((float)var);
    }
    float wsum = li;
    #pragma unroll
    for (int off = 32; off > 0; off >>= 1) wsum += __shfl_down(wsum, off, 64);
    if (tid == 0) atomicAdd(out, wsum * (1.0f / (float)C));
}

extern "C" void kernel_launch(void* const* d_in, const int* in_sizes, int n_in,
                              void* d_out, int out_size, void* d_ws, size_t ws_size,
                              hipStream_t stream) {
    const float* seq = (const float*)d_in[0];
    const int* src_len = (const int*)d_in[1];
    const void* comb = (const void*)d_in[2];
    float* out = (float*)d_out;

    const int B = in_sizes[1];
    const int C = in_sizes[2] / 2;
    const int T = in_sizes[0] / (B * D);
    const int RT = (T + NT - 1) / NT;       // phase kernels' row blocks
    const int RT256 = (T + 255) / 256;      // merge/final row blocks
    const int nrows = B * T;

    auto need = [&](int js, int ks) -> size_t {
        return (size_t)nrows * 4
             + ((size_t)2 * C * js * 36 * T + (size_t)2 * C * D * T) * 4
             + (size_t)2 * C * ks * 4 * T * 8;
    };
    int JS = 8, KS = 8;
    while (JS > 1 && need(JS, KS) > ws_size) { JS >>= 1; KS >>= 1; }

    hipMemsetAsync(out, 0, sizeof(float), stream);

    if (need(JS, KS) <= ws_size) {
        float* norms = (float*)d_ws;
        float* ws1 = norms + nrows;
        float* ws3 = ws1 + (size_t)2 * C * JS * 36 * T;
        double* ws2 = (double*)(ws3 + (size_t)2 * C * D * T);
        row_norms<<<(nrows + 63) / 64, 64, 0, stream>>>(seq, norms, nrows);
        ccl_phaseA<<<dim3(2 * C, RT, JS), NT, 0, stream>>>(seq, src_len, comb, norms, ws1, T, B, C, JS);
        ccl_merge_snn<<<dim3(2 * C, RT256), 256, 0, stream>>>(ws1, src_len, comb, ws3, T, B, C, JS);
        ccl_phaseB<<<dim3(2 * C, RT, KS), NT, 0, stream>>>(seq, src_len, comb, norms, ws3, ws2, T, B, C, KS);
        ccl_final<<<dim3(2 * C, RT256), 256, 0, stream>>>(ws2, src_len, comb, out, T, B, C, KS);
    } else {
        dim3 grid(2 * C, (T + 63) / 64);
        ccl_mono<<<grid, 64, 0, stream>>>(seq, src_len, comb, out, T, B, C);
    }
}

// Round 6
// 530.976 us; speedup vs baseline: 3.7689x; 1.5788x over previous
//
#include <hip/hip_runtime.h>

#define D 32
#define NT 128

__device__ __forceinline__ void decode_pair(const void* comb, int B, int C,
                                            int pair, int flip, int& a, int& b) {
    const long long* c64 = (const long long*)comb;
    const int* c32 = (const int*)comb;
    bool is64 = true;
    for (int q = 0; q < C; ++q) {
        long long v = c64[q];
        if (v < 0 || v >= (long long)B) { is64 = false; break; }
    }
    if (is64) { a = (int)c64[2 * pair]; b = (int)c64[2 * pair + 1]; }
    else      { a = c32[2 * pair];      b = c32[2 * pair + 1]; }
    if (flip) { int t = a; a = b; b = t; }
}

// ---------------- K0: per-row squared norms ----------------
__global__ __launch_bounds__(256)
void row_norms(const float* __restrict__ seq, float* __restrict__ norms, int nrows) {
    const int r = blockIdx.x * 256 + threadIdx.x;
    if (r >= nrows) return;
    const float* p = seq + (size_t)r * D;
    float s = 0.f;
    #pragma unroll
    for (int c = 0; c < 8; ++c) {
        float4 v = *(const float4*)(p + 4 * c);
        s = fmaf(v.x, v.x, fmaf(v.y, v.y, fmaf(v.z, v.z, fmaf(v.w, v.w, s))));
    }
    norms[r] = s;
}

// ---------------- K1: phase-A partial, branch-free fixed shift m = |x_i|^2 ----------------
// e_j = exp(2 x.y - |y|^2 - |x|^2) = exp(-d1) <= 1, no rescale ever needed.
// All chunks share the same shift -> merge is a plain sum.
// ws1 slot (33 fields, field-major): f=0: s, f=1..32: acc[d]
__global__ __launch_bounds__(NT)
void ccl_phaseA(const float* __restrict__ seq, const int* __restrict__ src_len,
                const void* __restrict__ comb, const float* __restrict__ norms,
                float* __restrict__ ws1, int T, int B, int C, int JS, int JC) {
    const int dir = blockIdx.x, pair = dir >> 1, flip = dir & 1;
    int a, b; decode_pair(comb, B, C, pair, flip, a, b);
    const int Lx = src_len[a] >> 2, Ly = src_len[b] >> 2;
    const int r0 = blockIdx.y * NT;
    if (r0 >= Lx) return;
    const int js = blockIdx.z;
    const int j0 = js * JC;
    if (j0 >= Ly) return;                  // empty chunk: exits, never merged
    const int j1 = min(Ly, j0 + JC);
    const int tid = threadIdx.x;
    const int i = r0 + tid;
    const int ic = min(i, Lx - 1);         // invalid lanes mirror a valid row

    const float* __restrict__ xbase = seq + (size_t)a * T * D;
    const float* __restrict__ ybase = seq + (size_t)b * T * D;
    const float* __restrict__ ny = norms + (size_t)b * T;

    float x2[D];
    {
        const float* xr = xbase + (size_t)ic * D;
        #pragma unroll
        for (int c = 0; c < 8; ++c) {
            float4 v = *(const float4*)(xr + 4 * c);
            x2[4*c]=2.f*v.x; x2[4*c+1]=2.f*v.y; x2[4*c+2]=2.f*v.z; x2[4*c+3]=2.f*v.w;
        }
    }
    const float negc = -norms[(size_t)a * T + ic];   // -|x_i|^2

    float s = 0.f;
    float acc[D];
    #pragma unroll
    for (int d = 0; d < D; ++d) acc[d] = 0.f;

    #pragma unroll 2
    for (int j = j0; j < j1; ++j) {
        const float* yr = ybase + (size_t)j * D;     // wave-uniform address
        float yv[D];
        #pragma unroll
        for (int c = 0; c < 8; ++c) *(float4*)&yv[4*c] = *(const float4*)(yr + 4*c);
        float d0 = negc - ny[j], d1 = 0.f, d2 = 0.f, d3 = 0.f;
        #pragma unroll
        for (int d = 0; d < D; d += 4) {
            d0 = fmaf(x2[d+0], yv[d+0], d0);
            d1 = fmaf(x2[d+1], yv[d+1], d1);
            d2 = fmaf(x2[d+2], yv[d+2], d2);
            d3 = fmaf(x2[d+3], yv[d+3], d3);
        }
        const float e = __expf((d0 + d1) + (d2 + d3));   // exp(-d1_ij) <= ~1
        s += e;
        #pragma unroll
        for (int d = 0; d < D; ++d) acc[d] = fmaf(e, yv[d], acc[d]);
    }

    if (i < T) {
        float* slot = ws1 + (size_t)(dir * JS + js) * 33 * T;
        slot[i] = s;
        #pragma unroll
        for (int d = 0; d < D; ++d) slot[(size_t)(1 + d) * T + i] = acc[d];
    }
}

// ---------------- K1.5: merge -> ws3 fields 0..31 = 2*snn, 32 = -|snn|^2 ----------------
__global__ __launch_bounds__(NT)
void ccl_merge_snn(const float* __restrict__ ws1, const int* __restrict__ src_len,
                   const void* __restrict__ comb, float* __restrict__ ws3,
                   int T, int B, int C, int JS, int JC) {
    const int dir = blockIdx.x, pair = dir >> 1, flip = dir & 1;
    int a, b; decode_pair(comb, B, C, pair, flip, a, b);
    const int Lx = src_len[a] >> 2, Ly = src_len[b] >> 2;
    const int r0 = blockIdx.y * NT;
    if (r0 >= Lx) return;
    const int i = r0 + threadIdx.x;
    if (i >= T) return;
    const int nch = min(JS, (Ly + JC - 1) / JC);

    float S = 0.f;
    float sn[D];
    #pragma unroll
    for (int d = 0; d < D; ++d) sn[d] = 0.f;
    for (int ch = 0; ch < nch; ++ch) {
        const float* slot = ws1 + (size_t)(dir * JS + ch) * 33 * T;
        S += slot[i];
        #pragma unroll
        for (int d = 0; d < D; ++d) sn[d] += slot[(size_t)(1 + d) * T + i];
    }
    const float inv = 1.f / S;
    float m2 = 0.f;
    #pragma unroll
    for (int d = 0; d < D; ++d) { sn[d] *= inv; m2 = fmaf(sn[d], sn[d], m2); }
    float* o = ws3 + (size_t)dir * 33 * T;
    #pragma unroll
    for (int d = 0; d < D; ++d) o[(size_t)d * T + i] = 2.f * sn[d];
    o[(size_t)D * T + i] = -m2;
}

// ---------------- K2: phase-B partial, branch-free shift m = |snn_i|^2, fp64 moments ----------------
// ws2 slot (3 double fields): f=0: s, f=1: s1, f=2: s2
__global__ __launch_bounds__(NT)
void ccl_phaseB(const float* __restrict__ seq, const int* __restrict__ src_len,
                const void* __restrict__ comb, const float* __restrict__ norms,
                const float* __restrict__ ws3, double* __restrict__ ws2,
                int T, int B, int C, int KS, int KC) {
    const int dir = blockIdx.x, pair = dir >> 1, flip = dir & 1;
    int a, b; decode_pair(comb, B, C, pair, flip, a, b);
    const int Lx = src_len[a] >> 2;
    const int r0 = blockIdx.y * NT;
    if (r0 >= Lx) return;
    const int ks = blockIdx.z;
    const int k0 = ks * KC;
    if (k0 >= Lx) return;
    const int k1 = min(Lx, k0 + KC);
    const int tid = threadIdx.x;
    const int i = r0 + tid;
    const int ic = min(i, T - 1);

    const float* __restrict__ xbase = seq + (size_t)a * T * D;
    const float* __restrict__ nx = norms + (size_t)a * T;

    float sn2[D];
    {
        const float* p = ws3 + (size_t)dir * 33 * T + ic;
        #pragma unroll
        for (int d = 0; d < D; ++d) sn2[d] = p[(size_t)d * T];
    }
    const float negc = ws3[(size_t)dir * 33 * T + (size_t)D * T + ic];  // -|snn|^2

    double sb = 0.0, s1 = 0.0, s2 = 0.0;
    const float fi = (float)i;

    #pragma unroll 2
    for (int k = k0; k < k1; ++k) {
        const float* xr = xbase + (size_t)k * D;     // wave-uniform address
        float xv[D];
        #pragma unroll
        for (int c = 0; c < 8; ++c) *(float4*)&xv[4*c] = *(const float4*)(xr + 4*c);
        float d0 = negc - nx[k], d1 = 0.f, d2 = 0.f, d3 = 0.f;
        #pragma unroll
        for (int d = 0; d < D; d += 4) {
            d0 = fmaf(sn2[d+0], xv[d+0], d0);
            d1 = fmaf(sn2[d+1], xv[d+1], d1);
            d2 = fmaf(sn2[d+2], xv[d+2], d2);
            d3 = fmaf(sn2[d+3], xv[d+3], d3);
        }
        const float e = __expf((d0 + d1) + (d2 + d3));   // exp(-d2_ik)
        const float kc = (float)k - fi;                  // centered index
        const double ed = (double)e;
        const double kcd = (double)kc;
        sb += ed;
        s1 = fma(ed, kcd, s1);
        s2 = fma(ed * kcd, kcd, s2);
    }

    if (i < T) {
        double* slot = ws2 + (size_t)(dir * KS + ks) * 3 * T;
        slot[i] = sb;
        slot[(size_t)T + i] = s1;
        slot[(size_t)2 * T + i] = s2;
    }
}

// ---------------- K3: merge phase-B partials -> li -> sum ----------------
__global__ __launch_bounds__(NT)
void ccl_final(const double* __restrict__ ws2, const int* __restrict__ src_len,
               const void* __restrict__ comb, float* __restrict__ out,
               int T, int B, int C, int KS, int KC) {
    const int dir = blockIdx.x, pair = dir >> 1, flip = dir & 1;
    int a, b; decode_pair(comb, B, C, pair, flip, a, b);
    const int Lx = src_len[a] >> 2;
    const int r0 = blockIdx.y * NT;
    if (r0 >= Lx) return;
    const int tid = threadIdx.x;
    const int i = r0 + tid;
    const int nch = min(KS, (Lx + KC - 1) / KC);

    float li = 0.f;
    if (i < Lx) {
        double S = 0.0, S1 = 0.0, S2 = 0.0;
        for (int ch = 0; ch < nch; ++ch) {
            const double* slot = ws2 + (size_t)(dir * KS + ch) * 3 * T;
            S  += slot[i];
            S1 += slot[(size_t)T + i];
            S2 += slot[(size_t)2 * T + i];
        }
        const double inv = 1.0 / S;
        const double du = S1 * inv;                    // u - i
        const double var = fma(-du, du, S2 * inv);     // E[(k-i)^2] - (u-i)^2
        li = (float)(du * du / var) + 0.005f * __logf((float)var);
    }

    float wsum = li;
    #pragma unroll
    for (int off = 32; off > 0; off >>= 1) wsum += __shfl_down(wsum, off, 64);
    __shared__ float red[NT / 64];
    if ((tid & 63) == 0) red[tid >> 6] = wsum;
    __syncthreads();
    if (tid == 0) {
        float t = 0.f;
        #pragma unroll
        for (int w = 0; w < NT / 64; ++w) t += red[w];
        atomicAdd(out, t / (float)C);
    }
}

// ---------------- Fallback: monolithic (known correct) ----------------
__global__ void ccl_mono(const float* __restrict__ seq, const int* __restrict__ src_len,
                         const void* __restrict__ comb, float* __restrict__ out,
                         int T, int B, int C) {
    const int dir = blockIdx.x, pair = dir >> 1, flip = dir & 1;
    int a, b; decode_pair(comb, B, C, pair, flip, a, b);
    const int Lx = src_len[a] >> 2, Ly = src_len[b] >> 2;
    if (blockIdx.y * 64 >= Lx) return;
    const int tid = threadIdx.x;
    const int i = blockIdx.y * 64 + tid;
    const bool valid = (i < Lx);
    const float* __restrict__ xbase = seq + (size_t)a * T * D;
    const float* __restrict__ ybase = seq + (size_t)b * T * D;
    float x[D];
    {
        const float* xr = xbase + (size_t)(valid ? i : (Lx - 1)) * D;
        #pragma unroll
        for (int c = 0; c < 8; ++c) {
            float4 v = *(const float4*)(xr + 4 * c);
            x[4*c] = 2.f*v.x; x[4*c+1] = 2.f*v.y; x[4*c+2] = 2.f*v.z; x[4*c+3] = 2.f*v.w;
        }
    }
    float m = -3.4e38f, s = 0.f;
    float acc[D];
    #pragma unroll
    for (int d = 0; d < D; ++d) acc[d] = 0.f;
    for (int j = 0; j < Ly; ++j) {
        const float* yr = ybase + (size_t)j * D;
        float yv[D]; float q2 = 0.f;
        #pragma unroll
        for (int d = 0; d < D; ++d) { yv[d] = yr[d]; q2 = fmaf(yv[d], yv[d], q2); }
        float d0 = -q2, d1 = 0.f, d2 = 0.f, d3 = 0.f;
        #pragma unroll
        for (int d = 0; d < D; d += 4) {
            d0 = fmaf(x[d], yv[d], d0); d1 = fmaf(x[d+1], yv[d+1], d1);
            d2 = fmaf(x[d+2], yv[d+2], d2); d3 = fmaf(x[d+3], yv[d+3], d3);
        }
        const float sc = (d0 + d1) + (d2 + d3);
        if (__any(sc > m + 8.f)) {
            const float mn = fmaxf(m, sc);
            const float scale = __expf(m - mn);
            const float e = __expf(sc - mn);
            s = fmaf(s, scale, e);
            #pragma unroll
            for (int d = 0; d < D; ++d) acc[d] = fmaf(acc[d], scale, e * yv[d]);
            m = mn;
        } else {
            const float e = __expf(sc - m);
            s += e;
            #pragma unroll
            for (int d = 0; d < D; ++d) acc[d] = fmaf(e, yv[d], acc[d]);
        }
    }
    { const float inv_s = 2.f / s;
      #pragma unroll
      for (int d = 0; d < D; ++d) acc[d] *= inv_s; }
    float mb = -3.4e38f;
    double sb = 0.0, s1 = 0.0, s2m = 0.0;
    const float fi = (float)i;
    for (int k = 0; k < Lx; ++k) {
        const float* xr = xbase + (size_t)k * D;
        float xv[D]; float q2 = 0.f;
        #pragma unroll
        for (int d = 0; d < D; ++d) { xv[d] = xr[d]; q2 = fmaf(xv[d], xv[d], q2); }
        float d0 = -q2, d1 = 0.f, d2 = 0.f, d3 = 0.f;
        #pragma unroll
        for (int d = 0; d < D; d += 4) {
            d0 = fmaf(acc[d], xv[d], d0); d1 = fmaf(acc[d+1], xv[d+1], d1);
            d2 = fmaf(acc[d+2], xv[d+2], d2); d3 = fmaf(acc[d+3], xv[d+3], d3);
        }
        const float sc = (d0 + d1) + (d2 + d3);
        const float kc = (float)k - fi;
        if (__any(sc > mb + 8.f)) {
            const float mn = fmaxf(mb, sc);
            const double scale = (double)__expf(mb - mn);
            const double e = (double)__expf(sc - mn);
            sb = sb * scale + e; s1 = s1 * scale + e * kc; s2m = s2m * scale + e * kc * kc;
            mb = mn;
        } else {
            const double e = (double)__expf(sc - mb);
            sb += e; s1 = fma(e, (double)kc, s1); s2m = fma(e * kc, (double)kc, s2m);
        }
    }
    float li = 0.f;
    if (valid) {
        const double inv = 1.0 / sb;
        const double du = s1 * inv;
        const double var = fma(-du, du, s2m * inv);
        li = (float)(du * du / var) + 0.005f * __logf((float)var);
    }
    float wsum = li;
    #pragma unroll
    for (int off = 32; off > 0; off >>= 1) wsum += __shfl_down(wsum, off, 64);
    if (tid == 0) atomicAdd(out, wsum * (1.0f / (float)C));
}

extern "C" void kernel_launch(void* const* d_in, const int* in_sizes, int n_in,
                              void* d_out, int out_size, void* d_ws, size_t ws_size,
                              hipStream_t stream) {
    const float* seq = (const float*)d_in[0];
    const int* src_len = (const int*)d_in[1];
    const void* comb = (const void*)d_in[2];
    float* out = (float*)d_out;

    const int B = in_sizes[1];
    const int C = in_sizes[2] / 2;
    const int T = in_sizes[0] / (B * D);
    const int RT = (T + NT - 1) / NT;
    const int nrows = B * T;

    auto need = [&](int js, int ks) -> size_t {
        return 4 * ((size_t)nrows + (size_t)2 * C * js * 33 * T + (size_t)2 * C * 33 * T)
             + 8 * (size_t)2 * C * ks * 3 * T;
    };
    int JS = 16, KS = 16;
    while (JS > 1 && need(JS, KS) > ws_size) { JS >>= 1; KS >>= 1; }

    hipMemsetAsync(out, 0, sizeof(float), stream);

    if (need(JS, KS) <= ws_size) {
        const int JC = (T + JS - 1) / JS;
        const int KC = (T + KS - 1) / KS;
        float* norms = (float*)d_ws;
        float* ws1 = norms + nrows;
        float* ws3 = ws1 + (size_t)2 * C * JS * 33 * T;
        double* ws2 = (double*)(ws3 + (size_t)2 * C * 33 * T);
        row_norms<<<(nrows + 255) / 256, 256, 0, stream>>>(seq, norms, nrows);
        ccl_phaseA<<<dim3(2 * C, RT, JS), NT, 0, stream>>>(seq, src_len, comb, norms, ws1, T, B, C, JS, JC);
        ccl_merge_snn<<<dim3(2 * C, RT), NT, 0, stream>>>(ws1, src_len, comb, ws3, T, B, C, JS, JC);
        ccl_phaseB<<<dim3(2 * C, RT, KS), NT, 0, stream>>>(seq, src_len, comb, norms, ws3, ws2, T, B, C, KS, KC);
        ccl_final<<<dim3(2 * C, RT), NT, 0, stream>>>(ws2, src_len, comb, out, T, B, C, KS, KC);
    } else {
        dim3 grid(2 * C, (T + 63) / 64);
        ccl_mono<<<grid, 64, 0, stream>>>(seq, src_len, comb, out, T, B, C);
    }
}